// Round 3
// baseline (10318.610 us; speedup 1.0000x reference)
//
#include <hip/hip_runtime.h>
#include <hip/hip_fp16.h>

// Persistent clustered LSTM scan for MI355X — round 3.
// Round-1 structure (cooperative LDS staging of h, proven 5.7us/step) plus:
//  - per-producer release flags + 32-lane parallel poll (no contended RMW)
//  - f16 h-exchange (half the bytes)
//  - x staging + ys stores moved AFTER the flag raise (off inter-WG critical path)
//  - x prefetch issued after h loads (fence no longer stalls on HBM prefetch)
// 4 clusters x 16 batch rows; 32 WGs/cluster; WG = 256 thr (4 waves), 1 WG/CU.
// Wave w == gate w (i,f,g,o). Weights persistent in registers (f16).

typedef _Float16 f16x8 __attribute__((ext_vector_type(8)));
typedef _Float16 f16x4 __attribute__((ext_vector_type(4)));
typedef float    f32x4 __attribute__((ext_vector_type(4)));

__device__ __forceinline__ float sigmoid_f(float v) {
    return 1.f / (1.f + __expf(-v));
}
__device__ __forceinline__ float tanh_f(float v) {
    v = fminf(15.f, fmaxf(-15.f, v));
    const float e = __expf(2.f * v);
    return (e - 1.f) / (e + 1.f);
}

__global__ __launch_bounds__(256, 1)
void lstm_persistent(const float* __restrict__ x,
                     const float* __restrict__ c0,
                     const float* __restrict__ h0,
                     const float* __restrict__ Wi,
                     const float* __restrict__ Wh,
                     const float* __restrict__ bias,
                     float* __restrict__ out,
                     unsigned* __restrict__ flags,   // 4 clusters x 32 wg
                     _Float16* __restrict__ exch)    // 2 x 64 x 512 f16
{
    const int bid  = blockIdx.x;
    const int cl   = (bid & 7) >> 1;                 // 0..3 (cluster on 2 XCDs)
    const int wg   = ((bid >> 3) << 1) | (bid & 1);  // 0..31 within cluster
    const int tid  = threadIdx.x;
    const int w    = tid >> 6;                       // wave == gate
    const int lane = tid & 63;
    const int q    = lane >> 4;
    const int n16  = lane & 15;

    const int gb0  = cl * 16;
    const int col0 = wg * 16;

    // Combined A rows: [x(512) | h(512)] f16, physical = (logical + 8*row) & 1023
    __shared__ _Float16 Alds[16 * 1024];             // 32 KB
    __shared__ float    glds[4][16][20];             // stride 20: <=2-way (free)

    unsigned* myflags = flags + cl * 32;
    _Float16* exbuf0 = exch;
    _Float16* exbuf1 = exch + 64 * 512;

    // ---------------- B preload: persistent weight fragments -------------------
    // B[k][n]: lane n = lane&15, k = quad*8 + j per K=32 step.
    f16x8 Breg[32];
    {
        const int cg = w * 512 + col0 + n16;
#pragma unroll
        for (int kk = 0; kk < 32; ++kk) {
            const int kbase = kk * 32 + q * 8;
            f16x8 v;
#pragma unroll
            for (int j = 0; j < 8; ++j) {
                const int k = kbase + j;
                const float f = (k < 512) ? Wi[(size_t)k * 2048 + cg]
                                          : Wh[(size_t)(k - 512) * 2048 + cg];
                v[j] = (_Float16)f;
            }
            Breg[kk] = v;
        }
    }

    // ---------------- elementwise state: thread -> (batch eb, col ej) ----------
    const int eb = tid >> 4;
    const int ej = tid & 15;
    const float bi_i = bias[0 * 512 + col0 + ej];
    const float bi_f = bias[1 * 512 + col0 + ej];
    const float bi_g = bias[2 * 512 + col0 + ej];
    const float bi_o = bias[3 * 512 + col0 + ej];
    float cst = c0[(size_t)(gb0 + eb) * 512 + col0 + ej];

    // staging geometry (also used for h exchange): row hb, 32-f16 column block
    const int hb   = tid >> 4;                       // 0..15
    const int hcol = (tid & 15) * 32;                // 0..480

    // ---------------- pre-loop: load + stage x_0 -------------------------------
    float4 xr[8];
#pragma unroll
    for (int cc = 0; cc < 8; ++cc) {
        const int chunk = tid + cc * 256;
        const int b  = chunk >> 7;
        const int k4 = chunk & 127;
        xr[cc] = *(const float4*)&x[(size_t)(gb0 + b) * 1024 * 512 + k4 * 4];
    }
#pragma unroll
    for (int cc = 0; cc < 8; ++cc) {
        const int chunk = tid + cc * 256;
        const int b = chunk >> 7;
        const int k = (chunk & 127) * 4;
        f16x4 v;
        v[0] = (_Float16)xr[cc].x; v[1] = (_Float16)xr[cc].y;
        v[2] = (_Float16)xr[cc].z; v[3] = (_Float16)xr[cc].w;
        *(f16x4*)&Alds[b * 1024 + ((k + 8 * b) & 1023)] = v;
    }
    // prefetch x_1 (consumed at end of step 0)
#pragma unroll
    for (int cc = 0; cc < 8; ++cc) {
        const int chunk = tid + cc * 256;
        const int b  = chunk >> 7;
        const int k4 = chunk & 127;
        xr[cc] = *(const float4*)&x[((size_t)(gb0 + b) * 1024 + 1) * 512 + k4 * 4];
    }

    for (int t = 0; t < 1024; ++t) {
        // ---- wait for h_t: 32-lane parallel relaxed poll + acquire fence -------
        if (t > 0) {
            if (lane < 32) {
                const unsigned* f = myflags + lane;
                const unsigned tgt = (unsigned)t;
                int guard = 1 << 18;                 // deadlock safety valve
                while (__hip_atomic_load(f, __ATOMIC_RELAXED,
                                         __HIP_MEMORY_SCOPE_AGENT) < tgt) {
                    __builtin_amdgcn_s_sleep(1);
                    if (--guard == 0) break;
                }
            }
            __builtin_amdgcn_fence(__ATOMIC_ACQUIRE, "agent");
        }

        // ---- cooperative h_t staging into LDS (1x traffic, all 256 threads) ----
        if (t == 0) {
            const float* hrow = h0 + (size_t)(gb0 + hb) * 512 + hcol;
            float4 a[8];
#pragma unroll
            for (int j = 0; j < 8; ++j) a[j] = *(const float4*)&hrow[j * 4];
#pragma unroll
            for (int i = 0; i < 4; ++i) {
                f16x8 v;
                v[0]=(_Float16)a[2*i].x;   v[1]=(_Float16)a[2*i].y;
                v[2]=(_Float16)a[2*i].z;   v[3]=(_Float16)a[2*i].w;
                v[4]=(_Float16)a[2*i+1].x; v[5]=(_Float16)a[2*i+1].y;
                v[6]=(_Float16)a[2*i+1].z; v[7]=(_Float16)a[2*i+1].w;
                *(f16x8*)&Alds[hb * 1024 + ((512 + hcol + 8 * i + 8 * hb) & 1023)] = v;
            }
        } else {
            const unsigned long long* src = (const unsigned long long*)
                (((t & 1) ? exbuf1 : exbuf0) + (size_t)(gb0 + hb) * 512 + hcol);
            unsigned long long u[8];
#pragma unroll
            for (int j = 0; j < 8; ++j)
                u[j] = __hip_atomic_load(&src[j], __ATOMIC_RELAXED,
                                         __HIP_MEMORY_SCOPE_AGENT);
            // issue x_{t+2} prefetch while h loads are in flight
            if (t < 1022) {
#pragma unroll
                for (int cc = 0; cc < 8; ++cc) {
                    const int chunk = tid + cc * 256;
                    const int b  = chunk >> 7;
                    const int k4 = chunk & 127;
                    // NOTE: xr currently holds x_{t+1}; it is staged at end of
                    // step t BEFORE this prefetch's values are needed -- but we
                    // must not clobber xr before staging. Stage into xr2 below.
                }
            }
#pragma unroll
            for (int i = 0; i < 4; ++i) {
                union { unsigned long long uu[2]; f16x8 v; } c;
                c.uu[0] = u[2 * i]; c.uu[1] = u[2 * i + 1];
                *(f16x8*)&Alds[hb * 1024 + ((512 + hcol + 8 * i + 8 * hb) & 1023)] = c.v;
            }
        }
        __syncthreads();                              // A: x_t + h_t staged

        // ---- GEMM: C[16b x 16col] = A[16 x 1024] * Breg ------------------------
        f32x4 acc0 = {0.f, 0.f, 0.f, 0.f}, acc1 = {0.f, 0.f, 0.f, 0.f};
        {
            const int m   = n16;
            const int rot = 8 * m;
#pragma unroll
            for (int kk = 0; kk < 32; kk += 2) {
                const int k0 = kk * 32 + q * 8;
                const f16x8 a0 = *(const f16x8*)&Alds[m * 1024 + ((k0      + rot) & 1023)];
                const f16x8 a1 = *(const f16x8*)&Alds[m * 1024 + ((k0 + 32 + rot) & 1023)];
                acc0 = __builtin_amdgcn_mfma_f32_16x16x32_f16(a0, Breg[kk],     acc0, 0, 0, 0);
                acc1 = __builtin_amdgcn_mfma_f32_16x16x32_f16(a1, Breg[kk + 1], acc1, 0, 0, 0);
            }
        }
        // C layout: col = lane&15, row = quad*4 + reg
#pragma unroll
        for (int r = 0; r < 4; ++r)
            glds[w][q * 4 + r][n16] = acc0[r] + acc1[r];
        __syncthreads();                              // B: gates ready, Alds free

        // ---- elementwise gates + state update ----------------------------------
        const float yi = glds[0][eb][ej] + bi_i;
        const float yf = glds[1][eb][ej] + bi_f;
        const float yg = glds[2][eb][ej] + bi_g;
        const float yo = glds[3][eb][ej] + bi_o;
        cst = sigmoid_f(yf) * cst + sigmoid_f(yi) * tanh_f(yg);
        const float hn = sigmoid_f(yo) * tanh_f(cst);

        // ---- publish h' as f16 pairs (4B agent stores) -------------------------
        if (t < 1023) {
            unsigned ub;
            { union { _Float16 h; unsigned short s; } c; c.h = (_Float16)hn; ub = c.s; }
            const unsigned pb = __shfl_xor((int)ub, 1);
            if ((ej & 1) == 0) {
                _Float16* dstbuf = ((t & 1) ? exbuf0 : exbuf1);   // buf[(t+1)&1]
                unsigned* dst = (unsigned*)(dstbuf + (size_t)(gb0 + eb) * 512 + col0 + ej);
                __hip_atomic_store(dst, ub | (pb << 16),
                                   __ATOMIC_RELAXED, __HIP_MEMORY_SCOPE_AGENT);
            }
        }
        __syncthreads();                              // C: all h' stores drained

        if (t < 1023 && tid == 0) {
            __hip_atomic_store(myflags + wg, (unsigned)(t + 1),
                               __ATOMIC_RELEASE, __HIP_MEMORY_SCOPE_AGENT);
        }

        // ======== everything below is OFF the inter-WG critical path ===========
        // ---- stage x_{t+1} (from xr) into Alds for next step -------------------
        if (t < 1023) {
#pragma unroll
            for (int cc = 0; cc < 8; ++cc) {
                const int chunk = tid + cc * 256;
                const int b = chunk >> 7;
                const int k = (chunk & 127) * 4;
                f16x4 v;
                v[0] = (_Float16)xr[cc].x; v[1] = (_Float16)xr[cc].y;
                v[2] = (_Float16)xr[cc].z; v[3] = (_Float16)xr[cc].w;
                *(f16x4*)&Alds[b * 1024 + ((k + 8 * b) & 1023)] = v;
            }
            // prefetch x_{t+2} for the next iteration's staging
            if (t < 1022) {
#pragma unroll
                for (int cc = 0; cc < 8; ++cc) {
                    const int chunk = tid + cc * 256;
                    const int b  = chunk >> 7;
                    const int k4 = chunk & 127;
                    xr[cc] = *(const float4*)&x[((size_t)(gb0 + b) * 1024 + (t + 2)) * 512 + k4 * 4];
                }
            }
        }

        // ---- outputs -----------------------------------------------------------
        out[65536 + ((size_t)(gb0 + eb) * 1024 + t) * 512 + col0 + ej] = hn;
        if (t == 1023) {
            out[(size_t)(gb0 + eb) * 512 + col0 + ej]         = cst;  // cT
            out[32768 + (size_t)(gb0 + eb) * 512 + col0 + ej] = hn;   // hT
        }
        // NOTE: no barrier here; next iteration's syncthreads(A) orders the
        // Alds x-staging against the next GEMM, and the poll gates h staging.
    }
}

extern "C" void kernel_launch(void* const* d_in, const int* in_sizes, int n_in,
                              void* d_out, int out_size, void* d_ws, size_t ws_size,
                              hipStream_t stream) {
    const float* x  = (const float*)d_in[0];
    const float* c0 = (const float*)d_in[1];
    const float* h0 = (const float*)d_in[2];
    const float* Wi = (const float*)d_in[3];
    const float* Wh = (const float*)d_in[4];
    const float* b  = (const float*)d_in[5];
    float* out = (float*)d_out;

    // ws: [0,1024) flags (4 clusters x 32 x u32, zeroed), then 2 x 64*512 f16
    hipMemsetAsync(d_ws, 0, 1024, stream);
    unsigned* flags = (unsigned*)d_ws;
    _Float16* exch  = (_Float16*)((char*)d_ws + 1024);

    hipLaunchKernelGGL(lstm_persistent, dim3(128), dim3(256), 0, stream,
                       x, c0, h0, Wi, Wh, b, out, flags, exch);
}